// Round 6
// baseline (454.523 us; speedup 1.0000x reference)
//
#include <hip/hip_runtime.h>
#include <math.h>

// N=M=8192, d=64, P=64, N_FT=1024 -> folded k = 1..512, active band contiguous
#define N_SRC 8192
#define D_DIM 64
#define P_SL  64
#define KH    512
#define NBLK  1024

// ws float offsets (header zeroed by 64 B host memset; rest written before read)
#define WS_NM    0                       // norm_max as float bits (int atomicMax)
#define WS_BARC  1                       // barrier arrival counter
#define WS_BARG  2                       // barrier generation
#define WS_CS    16                      // wk*C, wk*S per (p, k-kmin): P*KH*2
#define WS_A     (WS_CS + P_SL*KH*2)     // UNSCALED projections of x: P*N
#define WS_B2    (WS_A + P_SL*N_SRC)     // UNSCALED projections of y: P*N

#define LOG_THRESH (-23.0259f)           // ln(1e-10): tail adds <1e-6 to out
#define LGAMMA32    78.0922236f
#define TWO_PI2     19.7392088f

__device__ __forceinline__ void sincos2pi(float t, float& s, float& c) {
    // v_sin_f32 / v_cos_f32 take REVOLUTIONS; fract maps into valid range.
    float f = __builtin_amdgcn_fractf(t);
    s = __builtin_amdgcn_sinf(f);
    c = __builtin_amdgcn_cosf(f);
}

// Grid-wide sense barrier (R4-verified pattern, now 1024 blocks; co-residency
// guaranteed by __launch_bounds__(256,4) -> 4 blocks/CU x 256 CUs).
__device__ __forceinline__ void grid_barrier(unsigned* cnt, unsigned* gen) {
    __syncthreads();
    if (threadIdx.x == 0) {
        __threadfence();   // agent-scope release of phase writes (L2 writeback)
        unsigned g = __hip_atomic_load(gen, __ATOMIC_RELAXED, __HIP_MEMORY_SCOPE_AGENT);
        unsigned a = __hip_atomic_fetch_add(cnt, 1u, __ATOMIC_ACQ_REL, __HIP_MEMORY_SCOPE_AGENT);
        if (a == NBLK - 1u) {
            __hip_atomic_store(cnt, 0u, __ATOMIC_RELAXED, __HIP_MEMORY_SCOPE_AGENT);
            __hip_atomic_fetch_add(gen, 1u, __ATOMIC_RELEASE, __HIP_MEMORY_SCOPE_AGENT);
        } else {
            while (__hip_atomic_load(gen, __ATOMIC_ACQUIRE, __HIP_MEMORY_SCOPE_AGENT) == g)
                __builtin_amdgcn_s_sleep(2);
        }
    }
    __syncthreads();
}

__global__ __launch_bounds__(256, 4) void k_fused(const float* __restrict__ x,
                                                  const float* __restrict__ y,
                                                  const float* __restrict__ xw,
                                                  const float* __restrict__ scale,
                                                  const float* __restrict__ xis,
                                                  float* ws, float* __restrict__ out) {
    __shared__ float sC[64], sS[64];
    __shared__ int skmin, skmax;
    const int tid = threadIdx.x, b = blockIdx.x;
    unsigned* hdr = (unsigned*)ws;
    unsigned* cnt = hdr + WS_BARC;
    unsigned* gen = hdr + WS_BARG;

    // ---------- Phase A: norms + unscaled projections + zero CS/out ----------
    {
        int rblk = b & 63;              // 64 row-blocks x 256 threads = 16384 rows
        int q    = b >> 6;              // 0..15: 4 slices per thread
        int r = rblk * 256 + tid;
        int isx = (r < N_SRC);
        const float* src = isx ? (x + (size_t)r * D_DIM)
                               : (y + (size_t)(r - N_SRC) * D_DIM);
        float4 row[16];
        const float4* rp = (const float4*)src;
#pragma unroll
        for (int j = 0; j < 16; ++j) row[j] = rp[j];

        if (q == 0) {                   // 64 blocks cover all rows for the norm
            float ss = 0.f;
#pragma unroll
            for (int j = 0; j < 16; ++j) {
                ss = fmaf(row[j].x, row[j].x, ss); ss = fmaf(row[j].y, row[j].y, ss);
                ss = fmaf(row[j].z, row[j].z, ss); ss = fmaf(row[j].w, row[j].w, ss);
            }
            float nm = sqrtf(ss);
            for (int o = 32; o; o >>= 1) nm = fmaxf(nm, __shfl_xor(nm, o, 64));
            if ((tid & 63) == 0) atomicMax((int*)ws + WS_NM, __float_as_int(nm));
        }

        int gt = b * 256 + tid;         // 0..262143
        if (gt < P_SL * KH * 2) ws[WS_CS + gt] = 0.f;
        if (gt < N_SRC)         out[gt] = 0.f;

        int rr = isx ? r : r - N_SRC;
        float* dst = ws + (isx ? WS_A : WS_B2);
        for (int pi = 0; pi < 4; ++pi) {
            int p = q * 4 + pi;
            const float4* xi = (const float4*)(xis + p * D_DIM);  // uniform -> s_load
            float acc = 0.f;
#pragma unroll
            for (int j = 0; j < 16; ++j) {
                float4 u = xi[j];
                acc = fmaf(row[j].x, u.x, acc); acc = fmaf(row[j].y, u.y, acc);
                acc = fmaf(row[j].z, u.z, acc); acc = fmaf(row[j].w, u.w, acc);
            }
            dst[(size_t)p * N_SRC + rr] = acc;  // unscaled; sf folded later
        }
    }
    grid_barrier(cnt, gen);

    // ---------- band (recomputed per block, deterministic) ----------
    if (tid == 0) { skmin = 0x7fffffff; skmax = 0; }
    __syncthreads();
    const float nm = __int_as_float(((const int*)ws)[WS_NM]);
    const float sf = 0.3f / nm;
    const float sr = scale[0] * sf;
    const float a  = TWO_PI2 * sr * sr;   // 2*pi^2*sigma^2
    const float la = logf(a);
    for (int k = tid + 1; k <= KH; k += 256) {
        float logv = 32.f * la + 63.f * logf((float)k)
                   - a * (float)k * (float)k - LGAMMA32;
        if (logv > LOG_THRESH) { atomicMin(&skmin, k); atomicMax(&skmax, k); }
    }
    __syncthreads();
    const int kmin = skmin, kmax = skmax;
    const int kcnt = (kmax > 0) ? (kmax - kmin + 1) : 0;   // ~50 expected

    // ---------- Phase C: adjoint NDFT (lane = frequency) ----------
    if (kcnt > 0) {
        int p = b & 63, chunk = b >> 6;   // 16 chunks x 512 points
        int lane = tid & 63;
        int wv = __builtin_amdgcn_readfirstlane(tid >> 6);
        const float* ap = ws + WS_A + (size_t)p * N_SRC + chunk * 512 + wv * 128;
        const float* wp = xw + chunk * 512 + wv * 128;
        for (int kbase = 0; kbase < kcnt; kbase += 64) {
            __syncthreads();
            if (tid < 64) { sC[tid] = 0.f; sS[tid] = 0.f; }
            __syncthreads();
            float fk = (float)(kmin + kbase + lane) * sf;
            float ca = 0.f, sa = 0.f;
#pragma unroll 8
            for (int j = 0; j < 128; ++j) {   // wave-uniform addresses -> s_load
                float aj = ap[j], wj = wp[j];
                float t = fk * aj;
                float s, c; sincos2pi(t, s, c);
                ca = fmaf(wj, c, ca);
                sa = fmaf(wj, s, sa);
            }
            atomicAdd(&sC[lane], ca);
            atomicAdd(&sS[lane], sa);
            __syncthreads();
            int ki = kbase + tid;
            if (tid < 64 && ki < kcnt) {
                int kk = kmin + ki;
                float logv = 32.f * la + 63.f * logf((float)kk)
                           - a * (float)kk * (float)kk - LGAMMA32;
                float wk = ((kk == KH) ? 1.f : 2.f) * expf(logv) * (1.f / (float)P_SL);
                atomicAdd(ws + WS_CS + ((size_t)p * KH + ki) * 2 + 0, wk * sC[tid]);
                atomicAdd(ws + WS_CS + ((size_t)p * KH + ki) * 2 + 1, wk * sS[tid]);
            }
        }
    }
    grid_barrier(cnt, gen);

    // ---------- Phase D: forward NDFT, direct sincos, 2 slices/thread ----------
    if (kcnt > 0) {
        int m  = (b & 31) * 256 + tid;    // 32 m-blocks x 256
        int pg = b >> 5;                  // 0..31, 2 slices each
        float sum = 0.f;
        for (int pi = 0; pi < 2; ++pi) {
            int p = pg * 2 + pi;
            float bm = ws[WS_B2 + (size_t)p * N_SRC + m] * sf;
            const float2* cs = (const float2*)(ws + WS_CS) + (size_t)p * KH;
#pragma unroll 4
            for (int i = 0; i < kcnt; ++i) {
                float2 q = cs[i];         // wave-uniform -> s_load
                float t = bm * (float)(kmin + i);
                float s, c; sincos2pi(t, s, c);
                sum = fmaf(q.x, c, sum);
                sum = fmaf(q.y, s, sum);
            }
        }
        atomicAdd(out + m, sum);          // out zeroed in phase A
    }
}

extern "C" void kernel_launch(void* const* d_in, const int* in_sizes, int n_in,
                              void* d_out, int out_size, void* d_ws, size_t ws_size,
                              hipStream_t stream) {
    const float* x     = (const float*)d_in[0];
    const float* y     = (const float*)d_in[1];
    const float* xw    = (const float*)d_in[2];
    const float* scale = (const float*)d_in[3];
    const float* xis   = (const float*)d_in[4];
    float* ws  = (float*)d_ws;
    float* out = (float*)d_out;

    hipMemsetAsync(ws, 0, 64, stream);   // header: norm + barrier state
    k_fused<<<dim3(NBLK), dim3(256), 0, stream>>>(x, y, xw, scale, xis, ws, out);
}

// Round 8
// 176.528 us; speedup vs baseline: 2.5748x; 2.5748x over previous
//
#include <hip/hip_runtime.h>
#include <math.h>

// N=M=8192, d=64, P=64, N_FT=1024 -> folded k = 1..512, active band contiguous
#define N_SRC 8192
#define D_DIM 64
#define P_SL  64
#define KH    512
#define NBLK  1024

// ws INT offsets (no host memset: all compares tolerate 0xAAAAAAAA poison)
#define WS_NM    0                       // norm_max bits (int atomicMax; poison<0)
#define WS_GEN   8                       // barrier generation (block0 writes 1,2)
#define WS_FLAG  64                      // flags: block b at int WS_FLAG + 4*b (16KB)
// ws FLOAT offsets
#define WS_CS    8192                    // wk*C, wk*S per (p, k-kmin): P*KH*2
#define WS_A     (WS_CS + P_SL*KH*2)     // UNSCALED projections of x: P*N
#define WS_B2    (WS_A + P_SL*N_SRC)     // UNSCALED projections of y: P*N

#define LOG_THRESH (-23.0259f)           // ln(1e-10): tail adds <1e-6 to out
#define LGAMMA32    78.0922236f
#define TWO_PI2     19.7392088f

__device__ __forceinline__ void sincos2pi(float t, float& s, float& c) {
    // v_sin_f32 / v_cos_f32 take REVOLUTIONS; fract maps into valid range.
    float f = __builtin_amdgcn_fractf(t);
    s = __builtin_amdgcn_sinf(f);
    c = __builtin_amdgcn_cosf(f);
}

// Grid barrier, no RMWs, no acquire-in-spin. bar = 1, 2 (monotone).
// Arrival: threadfence + RELEASE store to own flag (independent lines, pipelined).
// Block 0 scans flags with RELAXED polls; others RELAXED-poll gen. One ACQUIRE
// fence (agent scope) after exit supplies the cache invalidate for phase data.
__device__ __forceinline__ void grid_barrier(int* wsu, int bar) {
    __syncthreads();
    const int tid = threadIdx.x, b = blockIdx.x;
    if (tid == 0) {
        __threadfence();  // agent release of phase writes (wb to coherence point)
        __hip_atomic_store(wsu + WS_FLAG + 4 * b, bar,
                           __ATOMIC_RELEASE, __HIP_MEMORY_SCOPE_AGENT);
    }
    if (b == 0) {
        for (int i = tid; i < NBLK; i += 256) {   // thread t: 4 flags
            while (__hip_atomic_load(wsu + WS_FLAG + 4 * i,
                                     __ATOMIC_RELAXED, __HIP_MEMORY_SCOPE_AGENT) < bar)
                __builtin_amdgcn_s_sleep(1);
        }
        __syncthreads();                          // all 1024 arrived
        if (tid == 0) {
            __builtin_amdgcn_fence(__ATOMIC_ACQUIRE, "agent");
            __hip_atomic_store(wsu + WS_GEN, bar,
                               __ATOMIC_RELEASE, __HIP_MEMORY_SCOPE_AGENT);
        }
        __syncthreads();
    } else {
        if (tid == 0) {
            while (__hip_atomic_load(wsu + WS_GEN,
                                     __ATOMIC_RELAXED, __HIP_MEMORY_SCOPE_AGENT) < bar)
                __builtin_amdgcn_s_sleep(8);
            __builtin_amdgcn_fence(__ATOMIC_ACQUIRE, "agent");
        }
        __syncthreads();
    }
}

__global__ __launch_bounds__(256, 4) void k_fused(const float* __restrict__ x,
                                                  const float* __restrict__ y,
                                                  const float* __restrict__ xw,
                                                  const float* __restrict__ scale,
                                                  const float* __restrict__ xis,
                                                  float* ws, float* __restrict__ out) {
    __shared__ float sC[64], sS[64];
    __shared__ int skmin, skmax;
    const int tid = threadIdx.x, b = blockIdx.x;
    int* wsu = (int*)ws;

    // ---------- Phase A: norms + unscaled projections + zero CS/out ----------
    {
        int rblk = b & 63;              // 64 row-blocks x 256 threads = 16384 rows
        int q    = b >> 6;              // 0..15 -> 4 slices per thread
        int r = rblk * 256 + tid;
        int isx = (r < N_SRC);
        const float* src = isx ? (x + (size_t)r * D_DIM)
                               : (y + (size_t)(r - N_SRC) * D_DIM);
        const float4* rp = (const float4*)src;

        if (q == 0) {                   // 64 blocks cover all rows for the norm
            float ss = 0.f;
#pragma unroll
            for (int j = 0; j < 16; ++j) {
                float4 v = rp[j];
                ss = fmaf(v.x, v.x, ss); ss = fmaf(v.y, v.y, ss);
                ss = fmaf(v.z, v.z, ss); ss = fmaf(v.w, v.w, ss);
            }
            float nm = sqrtf(ss);
            for (int o = 32; o; o >>= 1) nm = fmaxf(nm, __shfl_xor(nm, o, 64));
            if ((tid & 63) == 0) atomicMax((int*)ws + WS_NM, __float_as_int(nm));
        }

        int gt = b * 256 + tid;         // 0..262143
        if (gt < P_SL * KH * 2) ws[WS_CS + gt] = 0.f;
        if (gt < N_SRC)         out[gt] = 0.f;

        int rr = isx ? r : r - N_SRC;
        float* dst = ws + (isx ? WS_A : WS_B2);
        for (int pi = 0; pi < 4; ++pi) {
            int p = q * 4 + pi;
            const float4* xi = (const float4*)(xis + p * D_DIM);  // uniform -> s_load
            float acc = 0.f;
#pragma unroll
            for (int j = 0; j < 16; ++j) {
                float4 v = rp[j]; float4 u = xi[j];
                acc = fmaf(v.x, u.x, acc); acc = fmaf(v.y, u.y, acc);
                acc = fmaf(v.z, u.z, acc); acc = fmaf(v.w, u.w, acc);
            }
            dst[(size_t)p * N_SRC + rr] = acc;  // unscaled; sf folded later
        }
    }
    grid_barrier(wsu, 1);

    // ---------- band (recomputed per block, deterministic f32) ----------
    if (tid == 0) { skmin = 0x7fffffff; skmax = 0; }
    __syncthreads();
    const float nm = __int_as_float(wsu[WS_NM]);
    const float sf = 0.3f / nm;
    const float sr = scale[0] * sf;
    const float a  = TWO_PI2 * sr * sr;   // 2*pi^2*sigma^2
    const float la = logf(a);
    for (int k = tid + 1; k <= KH; k += 256) {
        float logv = 32.f * la + 63.f * logf((float)k)
                   - a * (float)k * (float)k - LGAMMA32;
        if (logv > LOG_THRESH) { atomicMin(&skmin, k); atomicMax(&skmax, k); }
    }
    __syncthreads();
    const int kmin = skmin, kmax = skmax;
    const int kcnt = (kmax > 0) ? (kmax - kmin + 1) : 0;   // ~50 expected

    // ---------- Phase C: adjoint NDFT (lane = frequency) ----------
    if (kcnt > 0) {
        int p = b & 63, chunk = b >> 6;   // 16 chunks x 512 points
        int lane = tid & 63;
        int wv = __builtin_amdgcn_readfirstlane(tid >> 6);
        const float* ap = ws + WS_A + (size_t)p * N_SRC + chunk * 512 + wv * 128;
        const float* wp = xw + chunk * 512 + wv * 128;
        for (int kbase = 0; kbase < kcnt; kbase += 64) {
            __syncthreads();
            if (tid < 64) { sC[tid] = 0.f; sS[tid] = 0.f; }
            __syncthreads();
            float fk = (float)(kmin + kbase + lane) * sf;
            float ca = 0.f, sa = 0.f;
#pragma unroll 8
            for (int j = 0; j < 128; ++j) {   // wave-uniform addresses -> s_load
                float aj = ap[j], wj = wp[j];
                float t = fk * aj;
                float s, c; sincos2pi(t, s, c);
                ca = fmaf(wj, c, ca);
                sa = fmaf(wj, s, sa);
            }
            atomicAdd(&sC[lane], ca);
            atomicAdd(&sS[lane], sa);
            __syncthreads();
            int ki = kbase + tid;
            if (tid < 64 && ki < kcnt) {
                int kk = kmin + ki;
                float logv = 32.f * la + 63.f * logf((float)kk)
                           - a * (float)kk * (float)kk - LGAMMA32;
                float wk = ((kk == KH) ? 1.f : 2.f) * expf(logv) * (1.f / (float)P_SL);
                atomicAdd(ws + WS_CS + ((size_t)p * KH + ki) * 2 + 0, wk * sC[tid]);
                atomicAdd(ws + WS_CS + ((size_t)p * KH + ki) * 2 + 1, wk * sS[tid]);
            }
        }
    }
    grid_barrier(wsu, 2);

    // ---------- Phase D: forward NDFT, direct sincos, 2 slices/thread ----------
    if (kcnt > 0) {
        int m  = (b & 31) * 256 + tid;    // 32 m-blocks x 256
        int pg = b >> 5;                  // 0..31, 2 slices each
        float sum = 0.f;
        for (int pi = 0; pi < 2; ++pi) {
            int p = pg * 2 + pi;
            float bm = ws[WS_B2 + (size_t)p * N_SRC + m] * sf;
            const float2* cs = (const float2*)(ws + WS_CS) + (size_t)p * KH;
#pragma unroll 4
            for (int i = 0; i < kcnt; ++i) {
                float2 q = cs[i];         // wave-uniform -> s_load
                float t = bm * (float)(kmin + i);
                float s, c; sincos2pi(t, s, c);
                sum = fmaf(q.x, c, sum);
                sum = fmaf(q.y, s, sum);
            }
        }
        atomicAdd(out + m, sum);          // out zeroed in phase A
    }
}

extern "C" void kernel_launch(void* const* d_in, const int* in_sizes, int n_in,
                              void* d_out, int out_size, void* d_ws, size_t ws_size,
                              hipStream_t stream) {
    const float* x     = (const float*)d_in[0];
    const float* y     = (const float*)d_in[1];
    const float* xw    = (const float*)d_in[2];
    const float* scale = (const float*)d_in[3];
    const float* xis   = (const float*)d_in[4];
    float* ws  = (float*)d_ws;
    float* out = (float*)d_out;

    // no memset: poison-tolerant header (monotone flag/gen compares, int atomicMax)
    k_fused<<<dim3(NBLK), dim3(256), 0, stream>>>(x, y, xw, scale, xis, ws, out);
}

// Round 9
// 129.376 us; speedup vs baseline: 3.5132x; 1.3645x over previous
//
#include <hip/hip_runtime.h>
#include <math.h>

// N=M=8192, d=64, P=64, N_FT=1024 -> folded k = 1..512, active band contiguous
#define N_SRC 8192
#define D_DIM 64
#define P_SL  64
#define KH    512
#define NBLK  1024

// ws INT offsets (no host memset: all compares tolerate 0xAAAAAAAA poison)
#define WS_NM    0                       // norm_max bits (int atomicMax; poison<0)
#define WS_GEN   32                      // barrier generation (separate line from NM)
#define WS_FLAG  64                      // flags: block b at int WS_FLAG + 4*b (16KB)
// ws FLOAT offsets
#define WS_CS    8192                    // wk*C, wk*S per (p, k-kmin): P*KH*2
#define WS_A     (WS_CS + P_SL*KH*2)     // UNSCALED projections of x: P*N
#define WS_B2    (WS_A + P_SL*N_SRC)     // UNSCALED projections of y: P*N

#define LOG_THRESH (-23.0259f)           // ln(1e-10): tail adds <1e-6 to out
#define LGAMMA32    78.0922236f
#define TWO_PI2     19.7392088f

__device__ __forceinline__ void sincos2pi(float t, float& s, float& c) {
    // v_sin_f32 / v_cos_f32 take REVOLUTIONS; fract maps into valid range.
    float f = __builtin_amdgcn_fractf(t);
    s = __builtin_amdgcn_sinf(f);
    c = __builtin_amdgcn_cosf(f);
}

// Grid barrier with NO cache invalidates (the R8 cost was ~4096 buffer_inv's).
// Arrival: agent RELEASE fence (waitcnt + L2 writeback only) + RELAXED flag
// store. Block 0 scans flags (RELAXED sc1 loads), stores GEN. Exit: RELAXED
// poll + workgroup acquire fence (compiler ordering only, no cache ops).
// Cross-block data is safe without invalidates: plain-written lines are only
// ever cached by their writer pre-barrier (written back by release); lines
// updated by device-scope atomics (CS) are read via device-scope loads only.
__device__ __forceinline__ void grid_barrier(int* wsu, int bar) {
    __syncthreads();
    const int tid = threadIdx.x, b = blockIdx.x;
    if (tid == 0) {
        __builtin_amdgcn_fence(__ATOMIC_RELEASE, "agent");   // wbl2, no inv
        __hip_atomic_store(wsu + WS_FLAG + 4 * b, bar,
                           __ATOMIC_RELAXED, __HIP_MEMORY_SCOPE_AGENT);
    }
    if (b == 0) {
        for (int i = tid; i < NBLK; i += 256) {   // thread t scans 4 flags
            while (__hip_atomic_load(wsu + WS_FLAG + 4 * i,
                                     __ATOMIC_RELAXED, __HIP_MEMORY_SCOPE_AGENT) < bar)
                __builtin_amdgcn_s_sleep(1);
        }
        __syncthreads();                          // all 1024 arrived
        if (tid == 0)
            __hip_atomic_store(wsu + WS_GEN, bar,
                               __ATOMIC_RELAXED, __HIP_MEMORY_SCOPE_AGENT);
    } else {
        if (tid == 0) {
            while (__hip_atomic_load(wsu + WS_GEN,
                                     __ATOMIC_RELAXED, __HIP_MEMORY_SCOPE_AGENT) < bar)
                __builtin_amdgcn_s_sleep(8);
        }
    }
    __builtin_amdgcn_fence(__ATOMIC_ACQUIRE, "workgroup");   // compiler barrier
    __syncthreads();
}

__global__ __launch_bounds__(256, 4) void k_fused(const float* __restrict__ x,
                                                  const float* __restrict__ y,
                                                  const float* __restrict__ xw,
                                                  const float* __restrict__ scale,
                                                  const float* __restrict__ xis,
                                                  float* ws, float* __restrict__ out) {
    __shared__ float sC[64], sS[64];
    __shared__ float2 sQ[2 * KH];        // phase D coefficient stage (8 KB)
    __shared__ int skmin, skmax;
    const int tid = threadIdx.x, b = blockIdx.x;
    int* wsu = (int*)ws;

    // ---------- Phase A: norms + unscaled projections + zero CS/out ----------
    {
        int rblk = b & 63;              // 64 row-blocks x 256 threads = 16384 rows
        int q    = b >> 6;              // 0..15 -> 4 slices per thread
        int r = rblk * 256 + tid;
        int isx = (r < N_SRC);
        const float* src = isx ? (x + (size_t)r * D_DIM)
                               : (y + (size_t)(r - N_SRC) * D_DIM);
        const float4* rp = (const float4*)src;

        if (q == 0) {                   // 64 blocks cover all rows for the norm
            float ss = 0.f;
#pragma unroll
            for (int j = 0; j < 16; ++j) {
                float4 v = rp[j];
                ss = fmaf(v.x, v.x, ss); ss = fmaf(v.y, v.y, ss);
                ss = fmaf(v.z, v.z, ss); ss = fmaf(v.w, v.w, ss);
            }
            float nm = sqrtf(ss);
            for (int o = 32; o; o >>= 1) nm = fmaxf(nm, __shfl_xor(nm, o, 64));
            if ((tid & 63) == 0) atomicMax((int*)ws + WS_NM, __float_as_int(nm));
        }

        int gt = b * 256 + tid;         // 0..262143
        if (gt < P_SL * KH * 2) ws[WS_CS + gt] = 0.f;
        if (gt < N_SRC)         out[gt] = 0.f;

        int rr = isx ? r : r - N_SRC;
        float* dst = ws + (isx ? WS_A : WS_B2);
        for (int pi = 0; pi < 4; ++pi) {
            int p = q * 4 + pi;
            const float4* xi = (const float4*)(xis + p * D_DIM);  // uniform -> s_load
            float acc = 0.f;
#pragma unroll
            for (int j = 0; j < 16; ++j) {
                float4 v = rp[j]; float4 u = xi[j];
                acc = fmaf(v.x, u.x, acc); acc = fmaf(v.y, u.y, acc);
                acc = fmaf(v.z, u.z, acc); acc = fmaf(v.w, u.w, acc);
            }
            dst[(size_t)p * N_SRC + rr] = acc;  // unscaled; sf folded later
        }
    }
    grid_barrier(wsu, 1);

    // ---------- band (recomputed per block, deterministic f32) ----------
    if (tid == 0) { skmin = 0x7fffffff; skmax = 0; }
    __syncthreads();
    const float nm = __int_as_float(wsu[WS_NM]);   // plain read: line never
    const float sf = 0.3f / nm;                    // plain-cached pre-write
    const float sr = scale[0] * sf;
    const float a  = TWO_PI2 * sr * sr;   // 2*pi^2*sigma^2
    const float la = logf(a);
    for (int k = tid + 1; k <= KH; k += 256) {
        float logv = 32.f * la + 63.f * logf((float)k)
                   - a * (float)k * (float)k - LGAMMA32;
        if (logv > LOG_THRESH) { atomicMin(&skmin, k); atomicMax(&skmax, k); }
    }
    __syncthreads();
    const int kmin = skmin, kmax = skmax;
    const int kcnt = (kmax > 0) ? (kmax - kmin + 1) : 0;   // ~50 expected

    // ---------- Phase C: adjoint NDFT (lane = frequency) ----------
    if (kcnt > 0) {
        int p = b & 63, chunk = b >> 6;   // 16 chunks x 512 points
        int lane = tid & 63;
        int wv = __builtin_amdgcn_readfirstlane(tid >> 6);
        const float* ap = ws + WS_A + (size_t)p * N_SRC + chunk * 512 + wv * 128;
        const float* wp = xw + chunk * 512 + wv * 128;
        for (int kbase = 0; kbase < kcnt; kbase += 64) {
            __syncthreads();
            if (tid < 64) { sC[tid] = 0.f; sS[tid] = 0.f; }
            __syncthreads();
            float fk = (float)(kmin + kbase + lane) * sf;
            float ca = 0.f, sa = 0.f;
#pragma unroll 8
            for (int j = 0; j < 128; ++j) {   // wave-uniform addresses -> s_load
                float aj = ap[j], wj = wp[j];
                float t = fk * aj;
                float s, c; sincos2pi(t, s, c);
                ca = fmaf(wj, c, ca);
                sa = fmaf(wj, s, sa);
            }
            atomicAdd(&sC[lane], ca);
            atomicAdd(&sS[lane], sa);
            __syncthreads();
            int ki = kbase + tid;
            if (tid < 64 && ki < kcnt) {
                int kk = kmin + ki;
                float logv = 32.f * la + 63.f * logf((float)kk)
                           - a * (float)kk * (float)kk - LGAMMA32;
                float wk = ((kk == KH) ? 1.f : 2.f) * expf(logv) * (1.f / (float)P_SL);
                // device-scope atomics: update IF$ directly, never dirty L2
                atomicAdd(ws + WS_CS + ((size_t)p * KH + ki) * 2 + 0, wk * sC[tid]);
                atomicAdd(ws + WS_CS + ((size_t)p * KH + ki) * 2 + 1, wk * sS[tid]);
            }
        }
    }
    grid_barrier(wsu, 2);

    // ---------- Phase D: forward NDFT, 2 slices/block, coeffs staged in LDS ----------
    if (kcnt > 0) {
        int m  = (b & 31) * 256 + tid;    // 32 m-blocks x 256
        int pg = b >> 5;                  // 0..31, 2 slices each
        // Stage CS via DEVICE-SCOPE loads (bypass L1/L2: zero-lines may be
        // stale-cached on their phase-A writer CU; truth lives in IF$).
        for (int pi = 0; pi < 2; ++pi) {
            const unsigned long long* cs64 =
                (const unsigned long long*)(ws + WS_CS) + (size_t)(pg * 2 + pi) * KH;
            for (int i = tid; i < kcnt; i += 256) {
                unsigned long long v = __hip_atomic_load(cs64 + i,
                        __ATOMIC_RELAXED, __HIP_MEMORY_SCOPE_AGENT);
                sQ[pi * KH + i] = make_float2(__uint_as_float((unsigned)v),
                                              __uint_as_float((unsigned)(v >> 32)));
            }
        }
        __syncthreads();
        float sum = 0.f;
        for (int pi = 0; pi < 2; ++pi) {
            int p = pg * 2 + pi;
            float bm = ws[WS_B2 + (size_t)p * N_SRC + m] * sf;
            const float2* cs = &sQ[pi * KH];
#pragma unroll 4
            for (int i = 0; i < kcnt; ++i) {
                float2 q = cs[i];         // LDS same-address broadcast
                float t = bm * (float)(kmin + i);
                float s, c; sincos2pi(t, s, c);
                sum = fmaf(q.x, c, sum);
                sum = fmaf(q.y, s, sum);
            }
        }
        atomicAdd(out + m, sum);          // out zeroed in phase A
    }
}

extern "C" void kernel_launch(void* const* d_in, const int* in_sizes, int n_in,
                              void* d_out, int out_size, void* d_ws, size_t ws_size,
                              hipStream_t stream) {
    const float* x     = (const float*)d_in[0];
    const float* y     = (const float*)d_in[1];
    const float* xw    = (const float*)d_in[2];
    const float* scale = (const float*)d_in[3];
    const float* xis   = (const float*)d_in[4];
    float* ws  = (float*)d_ws;
    float* out = (float*)d_out;

    // no memset: poison-tolerant header (monotone flag/gen compares, int atomicMax)
    k_fused<<<dim3(NBLK), dim3(256), 0, stream>>>(x, y, xw, scale, xis, ws, out);
}

// Round 10
// 122.626 us; speedup vs baseline: 3.7066x; 1.0550x over previous
//
#include <hip/hip_runtime.h>
#include <math.h>

// N=M=8192, d=64, P=64, N_FT=1024 -> folded k = 1..512, active band contiguous
#define N_SRC 8192
#define D_DIM 64
#define P_SL  64
#define KH    512
#define NBLK  1024

// ws INT offsets (no host memset: all compares tolerate 0xAAAAAAAA poison)
#define WS_NM    0                       // norm_max bits (int atomicMax; poison<0)
#define WS_GEN   32                      // barrier generation (separate line from NM)
#define WS_FLAG  64                      // flags: block b at int WS_FLAG + 4*b (16KB)
// ws FLOAT offsets
#define WS_CS    8192                    // wk*C, wk*S per (p, k-kmin): P*KH*2
#define WS_A     (WS_CS + P_SL*KH*2)     // UNSCALED projections of x: P*N
#define WS_B2    (WS_A + P_SL*N_SRC)     // UNSCALED projections of y: P*N

#define LOG_THRESH (-23.0259f)           // ln(1e-10): tail adds <1e-6 to out
#define LGAMMA32    78.0922236f
#define TWO_PI2     19.7392088f

__device__ __forceinline__ void sincos2pi(float t, float& s, float& c) {
    // v_sin_f32 / v_cos_f32 take REVOLUTIONS; fract maps into valid range.
    float f = __builtin_amdgcn_fractf(t);
    s = __builtin_amdgcn_sinf(f);
    c = __builtin_amdgcn_cosf(f);
}

// Grid barrier with NO cache invalidates (R9-verified). Arrival: agent RELEASE
// fence (waitcnt + L2 writeback, no inv) + RELAXED flag store to own slot.
// Block 0 scans flags RELAXED; others RELAXED-poll GEN. Exit: workgroup
// acquire fence (compiler ordering only). Cross-block data safety: plain-
// written lines only ever cached by their writer pre-barrier (released);
// atomic-updated lines (CS) are read via device-scope loads only.
__device__ __forceinline__ void grid_barrier(int* wsu, int bar) {
    __syncthreads();
    const int tid = threadIdx.x, b = blockIdx.x;
    if (tid == 0) {
        __builtin_amdgcn_fence(__ATOMIC_RELEASE, "agent");   // wbl2, no inv
        __hip_atomic_store(wsu + WS_FLAG + 4 * b, bar,
                           __ATOMIC_RELAXED, __HIP_MEMORY_SCOPE_AGENT);
    }
    if (b == 0) {
        for (int i = tid; i < NBLK; i += 256) {   // thread t scans 4 flags
            while (__hip_atomic_load(wsu + WS_FLAG + 4 * i,
                                     __ATOMIC_RELAXED, __HIP_MEMORY_SCOPE_AGENT) < bar)
                __builtin_amdgcn_s_sleep(1);
        }
        __syncthreads();                          // all 1024 arrived
        if (tid == 0)
            __hip_atomic_store(wsu + WS_GEN, bar,
                               __ATOMIC_RELAXED, __HIP_MEMORY_SCOPE_AGENT);
    } else {
        if (tid == 0) {
            while (__hip_atomic_load(wsu + WS_GEN,
                                     __ATOMIC_RELAXED, __HIP_MEMORY_SCOPE_AGENT) < bar)
                __builtin_amdgcn_s_sleep(8);
        }
    }
    __builtin_amdgcn_fence(__ATOMIC_ACQUIRE, "workgroup");   // compiler barrier
    __syncthreads();
}

__global__ __launch_bounds__(256, 4) void k_fused(const float* __restrict__ x,
                                                  const float* __restrict__ y,
                                                  const float* __restrict__ xw,
                                                  const float* __restrict__ scale,
                                                  const float* __restrict__ xis,
                                                  float* ws, float* __restrict__ out) {
    __shared__ float sC[64], sS[64];
    __shared__ float2 sBuf[2 * KH];      // phase C: (a,w) pairs; phase D: coeffs
    __shared__ int skmin, skmax;
    const int tid = threadIdx.x, b = blockIdx.x;
    int* wsu = (int*)ws;

    // ---------- Phase A: block owns 16 rows exclusively, all 64 slices ----------
    // tid = sg*16 + rowi. Loads: 16 lines x 4-lane broadcast per instr (vs 64-line
    // gather in R9); row chunk consumed for 4 slices immediately (no reload).
    {
        int rowi = tid & 15;            // 0..15
        int sg   = tid >> 4;            // 0..15 -> slices sg*4 .. sg*4+3
        int r    = b * 16 + rowi;       // 0..16383; block-uniform x/y split
        int isx  = (r < N_SRC);
        const float4* rp = (const float4*)(isx ? (x + (size_t)r * D_DIM)
                                               : (y + (size_t)(r - N_SRC) * D_DIM));
        const float4* xib = (const float4*)xis;   // [p*16 + j]
        int xb = sg * 64;               // (sg*4)*16
        float a0 = 0.f, a1 = 0.f, a2 = 0.f, a3 = 0.f, ss = 0.f;
#pragma unroll
        for (int j = 0; j < 16; ++j) {
            float4 v = rp[j];
            ss = fmaf(v.x, v.x, ss); ss = fmaf(v.y, v.y, ss);
            ss = fmaf(v.z, v.z, ss); ss = fmaf(v.w, v.w, ss);
            float4 u0 = xib[xb + j];
            float4 u1 = xib[xb + 16 + j];
            float4 u2 = xib[xb + 32 + j];
            float4 u3 = xib[xb + 48 + j];
            a0 = fmaf(v.x, u0.x, a0); a0 = fmaf(v.y, u0.y, a0);
            a0 = fmaf(v.z, u0.z, a0); a0 = fmaf(v.w, u0.w, a0);
            a1 = fmaf(v.x, u1.x, a1); a1 = fmaf(v.y, u1.y, a1);
            a1 = fmaf(v.z, u1.z, a1); a1 = fmaf(v.w, u1.w, a1);
            a2 = fmaf(v.x, u2.x, a2); a2 = fmaf(v.y, u2.y, a2);
            a2 = fmaf(v.z, u2.z, a2); a2 = fmaf(v.w, u2.w, a2);
            a3 = fmaf(v.x, u3.x, a3); a3 = fmaf(v.y, u3.y, a3);
            a3 = fmaf(v.z, u3.z, a3); a3 = fmaf(v.w, u3.w, a3);
        }
        int rr = isx ? r : r - N_SRC;
        float* dst = ws + (isx ? WS_A : WS_B2);
        int p0 = sg * 4;
        dst[(size_t)(p0 + 0) * N_SRC + rr] = a0;
        dst[(size_t)(p0 + 1) * N_SRC + rr] = a1;
        dst[(size_t)(p0 + 2) * N_SRC + rr] = a2;
        dst[(size_t)(p0 + 3) * N_SRC + rr] = a3;
        if (tid < 64) {                 // wave 0 lanes hold ss of rows (lane&15)
            float nm = sqrtf(ss);
            for (int o = 32; o; o >>= 1) nm = fmaxf(nm, __shfl_xor(nm, o, 64));
            if (tid == 0) atomicMax((int*)ws + WS_NM, __float_as_int(nm));
        }
        int gt = b * 256 + tid;         // 0..262143
        if (gt < P_SL * KH * 2) ws[WS_CS + gt] = 0.f;
        if (gt < N_SRC)         out[gt] = 0.f;
    }
    grid_barrier(wsu, 1);

    // ---------- band (recomputed per block, deterministic f32) ----------
    if (tid == 0) { skmin = 0x7fffffff; skmax = 0; }
    __syncthreads();
    const float nm = __int_as_float(wsu[WS_NM]);   // line never stale-cached
    const float sf = 0.3f / nm;
    const float sr = scale[0] * sf;
    const float a  = TWO_PI2 * sr * sr;   // 2*pi^2*sigma^2
    const float la = logf(a);
    for (int k = tid + 1; k <= KH; k += 256) {
        float logv = 32.f * la + 63.f * logf((float)k)
                   - a * (float)k * (float)k - LGAMMA32;
        if (logv > LOG_THRESH) { atomicMin(&skmin, k); atomicMax(&skmax, k); }
    }
    __syncthreads();
    const int kmin = skmin, kmax = skmax;
    const int kcnt = (kmax > 0) ? (kmax - kmin + 1) : 0;   // ~53 expected

    // ---------- Phase C: adjoint NDFT, lane=frequency, points staged in LDS ----------
    if (kcnt > 0) {
        int p = b & 63, chunk = b >> 6;   // 16 chunks x 512 points
        // stage 512 (a,w) pairs: one coalesced float2 round-trip each
        const float2* a2p = (const float2*)(ws + WS_A + (size_t)p * N_SRC + chunk * 512);
        const float2* w2p = (const float2*)(xw + chunk * 512);
        float2 av = a2p[tid];
        float2 wv = w2p[tid];
        sBuf[2 * tid]     = make_float2(av.x, wv.x);
        sBuf[2 * tid + 1] = make_float2(av.y, wv.y);
        int lane = tid & 63;
        int wvi  = tid >> 6;
        const float2* pt = &sBuf[wvi * 128];
        for (int kbase = 0; kbase < kcnt; kbase += 64) {
            __syncthreads();
            if (tid < 64) { sC[tid] = 0.f; sS[tid] = 0.f; }
            __syncthreads();
            float fk = (float)(kmin + kbase + lane) * sf;
            float ca = 0.f, sa = 0.f;
#pragma unroll 8
            for (int j = 0; j < 128; ++j) {   // ds_read_b64 broadcast, conflict-free
                float2 aw = pt[j];
                float t = fk * aw.x;
                float s, c; sincos2pi(t, s, c);
                ca = fmaf(aw.y, c, ca);
                sa = fmaf(aw.y, s, sa);
            }
            atomicAdd(&sC[lane], ca);
            atomicAdd(&sS[lane], sa);
            __syncthreads();
            int ki = kbase + tid;
            if (tid < 64 && ki < kcnt) {
                int kk = kmin + ki;
                float logv = 32.f * la + 63.f * logf((float)kk)
                           - a * (float)kk * (float)kk - LGAMMA32;
                float wk = ((kk == KH) ? 1.f : 2.f) * expf(logv) * (1.f / (float)P_SL);
                // device-scope atomics: update coherence point, never dirty L2
                atomicAdd(ws + WS_CS + ((size_t)p * KH + ki) * 2 + 0, wk * sC[tid]);
                atomicAdd(ws + WS_CS + ((size_t)p * KH + ki) * 2 + 1, wk * sS[tid]);
            }
        }
    }
    grid_barrier(wsu, 2);

    // ---------- Phase D: forward NDFT, 2 slices/block, coeffs staged in LDS ----------
    if (kcnt > 0) {
        int m  = (b & 31) * 256 + tid;    // 32 m-blocks x 256
        int pg = b >> 5;                  // 0..31, 2 slices each
        // Stage CS via DEVICE-SCOPE loads (bypass caches; truth is at coherence
        // point — zero-lines may be stale-cached on their phase-A writer CU).
        for (int pi = 0; pi < 2; ++pi) {
            const unsigned long long* cs64 =
                (const unsigned long long*)(ws + WS_CS) + (size_t)(pg * 2 + pi) * KH;
            for (int i = tid; i < kcnt; i += 256) {
                unsigned long long v = __hip_atomic_load(cs64 + i,
                        __ATOMIC_RELAXED, __HIP_MEMORY_SCOPE_AGENT);
                sBuf[pi * KH + i] = make_float2(__uint_as_float((unsigned)v),
                                                __uint_as_float((unsigned)(v >> 32)));
            }
        }
        __syncthreads();
        float sum = 0.f;
        for (int pi = 0; pi < 2; ++pi) {
            int p = pg * 2 + pi;
            float bm = ws[WS_B2 + (size_t)p * N_SRC + m] * sf;
            const float2* cs = &sBuf[pi * KH];
#pragma unroll 4
            for (int i = 0; i < kcnt; ++i) {
                float2 q = cs[i];         // LDS same-address broadcast
                float t = bm * (float)(kmin + i);
                float s, c; sincos2pi(t, s, c);
                sum = fmaf(q.x, c, sum);
                sum = fmaf(q.y, s, sum);
            }
        }
        atomicAdd(out + m, sum);          // out zeroed in phase A
    }
}

extern "C" void kernel_launch(void* const* d_in, const int* in_sizes, int n_in,
                              void* d_out, int out_size, void* d_ws, size_t ws_size,
                              hipStream_t stream) {
    const float* x     = (const float*)d_in[0];
    const float* y     = (const float*)d_in[1];
    const float* xw    = (const float*)d_in[2];
    const float* scale = (const float*)d_in[3];
    const float* xis   = (const float*)d_in[4];
    float* ws  = (float*)d_ws;
    float* out = (float*)d_out;

    // no memset: poison-tolerant header (monotone flag/gen compares, int atomicMax)
    k_fused<<<dim3(NBLK), dim3(256), 0, stream>>>(x, y, xw, scale, xis, ws, out);
}